// Round 6
// baseline (451.435 us; speedup 1.0000x reference)
//
#include <hip/hip_runtime.h>
#include <hip/hip_bf16.h>

// LightGCN: final = (ego + A·ego + A²·ego + A³·ego) / 4
// CSR build per call (bucket hist/scan + two-phase scatter, all L2-local writes).
// SpMM: bf16 features, 8 lanes/row (16B loads), unroll-2 dual-accumulator.
//   R=4 rows SERIAL per lane-group: wave critical path = max of 4-row sums
//   (Poisson degree divergence: ~35% masked iters at R=1 -> ~20% at R=4).
//   epack reads NON-TEMPORAL; y stores REGULAR (next layer's gather source, keep in L2).
// Layer 3 fused with final combine; ego read as bf16 from h0 (saves 38 MB f32 fetch).

#define NUM_USERS 100000
#define NUM_ITEMS 200000
#define NN (NUM_USERS + NUM_ITEMS)
#define DIM 64
#define BROWS 1024                              // rows per bucket
#define NB_BUCKETS ((NN + BROWS - 1) / BROWS)   // 293
#define CHUNK 4096                              // edges per binning block
#define RK 16                                   // reg-staged entries/thread (512*16 = 8192)
#define OVF 4096                                // LDS overflow entries in bucket_scatter

typedef unsigned short ushort8_t __attribute__((ext_vector_type(8)));
typedef float f32x4 __attribute__((ext_vector_type(4)));
typedef unsigned int u32x2 __attribute__((ext_vector_type(2)));

__device__ __forceinline__ float bf16_to_f32(unsigned short u) {
    return __uint_as_float(((unsigned int)u) << 16);
}
__device__ __forceinline__ unsigned short f32_to_bf16(float f) {
    unsigned int u = __float_as_uint(f);
    u += 0x7fffu + ((u >> 16) & 1u);   // round-to-nearest-even
    return (unsigned short)(u >> 16);
}

// ---------------- zero an int array ----------------
__global__ void zero_ints(int* __restrict__ p, int n) {
    int i = blockIdx.x * blockDim.x + threadIdx.x;
    if (i < n) p[i] = 0;
}

// ---------------- coarse bucket histogram (293 buckets) ----------------
__global__ __launch_bounds__(512) void bucket_hist(const int* __restrict__ rows,
                                                   int* __restrict__ bcnt, int E) {
    __shared__ int h[512];
    int t = threadIdx.x;
    h[t] = 0;
    __syncthreads();
    int base = blockIdx.x * CHUNK + t * 8;
    if (base + 8 <= E) {
        int4 r0 = *(const int4*)(rows + base);
        int4 r1 = *(const int4*)(rows + base + 4);
        atomicAdd(&h[r0.x >> 10], 1); atomicAdd(&h[r0.y >> 10], 1);
        atomicAdd(&h[r0.z >> 10], 1); atomicAdd(&h[r0.w >> 10], 1);
        atomicAdd(&h[r1.x >> 10], 1); atomicAdd(&h[r1.y >> 10], 1);
        atomicAdd(&h[r1.z >> 10], 1); atomicAdd(&h[r1.w >> 10], 1);
    } else {
        for (int k = 0; k < 8; ++k) {
            int e = base + k;
            if (e < E) atomicAdd(&h[rows[e] >> 10], 1);
        }
    }
    __syncthreads();
    if (t < NB_BUCKETS && h[t] > 0) atomicAdd(&bcnt[t], h[t]);
}

// ---------------- scan bucket counts -> bases; init cursors ----------------
__global__ void scan_buckets(const int* __restrict__ bcnt, int* __restrict__ bbase,
                             int* __restrict__ bcur, int* __restrict__ row_start, int E) {
    __shared__ int lds[512];
    int t = threadIdx.x;
    int v = bcnt[t];               // zeroed beyond NB_BUCKETS
    lds[t] = v;
    __syncthreads();
    for (int off = 1; off < 512; off <<= 1) {
        int u = (t >= off) ? lds[t - off] : 0;
        __syncthreads();
        lds[t] += u;
        __syncthreads();
    }
    int base = lds[t] - v;         // exclusive scan
    if (t <= NB_BUCKETS) bbase[t] = base;   // bbase[NB_BUCKETS] == E
    if (t < NB_BUCKETS)  bcur[t] = base;
    if (t == 0) row_start[NN] = E;
}

// ---------------- phase A: LDS-staged bucket binning ----------------
__global__ __launch_bounds__(512) void bin_edges(const int* __restrict__ rows,
                                                 const int* __restrict__ cols,
                                                 const float* __restrict__ vals,
                                                 int* __restrict__ bcur,
                                                 uint2* __restrict__ epack, int E) {
    __shared__ int lcnt[512];
    __shared__ int lscan[512];
    __shared__ int lcur[512];
    __shared__ int gbase[512];
    __shared__ uint2 stage[CHUNK];
    __shared__ int dstg[CHUNK];

    int t = threadIdx.x;
    int base = blockIdx.x * CHUNK;
    int n = E - base; if (n > CHUNK) n = CHUNK;

    lcnt[t] = 0;
    __syncthreads();

    int r[8], c[8], b[8];
    unsigned int vb[8];
    int ebase = base + t * 8;
    if (ebase + 8 <= E) {
        int4 r0 = *(const int4*)(rows + ebase);
        int4 r1 = *(const int4*)(rows + ebase + 4);
        int4 c0 = *(const int4*)(cols + ebase);
        int4 c1 = *(const int4*)(cols + ebase + 4);
        float4 v0 = *(const float4*)(vals + ebase);
        float4 v1 = *(const float4*)(vals + ebase + 4);
        r[0]=r0.x; r[1]=r0.y; r[2]=r0.z; r[3]=r0.w; r[4]=r1.x; r[5]=r1.y; r[6]=r1.z; r[7]=r1.w;
        c[0]=c0.x; c[1]=c0.y; c[2]=c0.z; c[3]=c0.w; c[4]=c1.x; c[5]=c1.y; c[6]=c1.z; c[7]=c1.w;
        vb[0]=__float_as_uint(v0.x); vb[1]=__float_as_uint(v0.y);
        vb[2]=__float_as_uint(v0.z); vb[3]=__float_as_uint(v0.w);
        vb[4]=__float_as_uint(v1.x); vb[5]=__float_as_uint(v1.y);
        vb[6]=__float_as_uint(v1.z); vb[7]=__float_as_uint(v1.w);
#pragma unroll
        for (int k = 0; k < 8; ++k) b[k] = r[k] >> 10;
    } else {
#pragma unroll
        for (int k = 0; k < 8; ++k) {
            int e = ebase + k;
            if (e < E) { r[k] = rows[e]; c[k] = cols[e]; vb[k] = __float_as_uint(vals[e]); b[k] = r[k] >> 10; }
            else b[k] = -1;
        }
    }
#pragma unroll
    for (int k = 0; k < 8; ++k)
        if (b[k] >= 0) atomicAdd(&lcnt[b[k]], 1);
    __syncthreads();

    // Hillis-Steele inclusive scan over 512 entries
    int val = lcnt[t];
    lscan[t] = val;
    __syncthreads();
    for (int off = 1; off < 512; off <<= 1) {
        int u = (t >= off) ? lscan[t - off] : 0;
        __syncthreads();
        lscan[t] += u;
        __syncthreads();
    }
    int excl = lscan[t] - val;
    lscan[t] = excl;          // exclusive local base (own-slot rewrite)
    lcur[t]  = excl;
    if (t < NB_BUCKETS && val > 0)
        gbase[t] = atomicAdd(&bcur[t], val);
    __syncthreads();

    // reorder into LDS (sorted by bucket), record global dst per slot
#pragma unroll
    for (int k = 0; k < 8; ++k) {
        int bb = b[k];
        if (bb >= 0) {
            int l = atomicAdd(&lcur[bb], 1);
            unsigned int w0 = (unsigned int)c[k] | (((unsigned int)(r[k] & (BROWS - 1))) << 19);
            stage[l] = make_uint2(w0, vb[k]);
            dstg[l] = gbase[bb] + (l - lscan[bb]);
        }
    }
    __syncthreads();

    // coalesced run writes
    for (int l = t; l < n; l += 512)
        epack[dstg[l]] = stage[l];
}

// ---------------- phase B: per-bucket row-hist + scan + exact CSR placement ----
__global__ __launch_bounds__(512) void bucket_scatter(const int* __restrict__ bbase,
                                                      int* __restrict__ row_start,
                                                      uint2* __restrict__ epack) {
    __shared__ int cur[BROWS];     // hist -> cursor
    __shared__ int stmp[512];
    __shared__ uint2 ovf[OVF];
    int b = blockIdx.x;
    int t = threadIdx.x;
    int rbase = b << 10;
    int nrows = NN - rbase; if (nrows > BROWS) nrows = BROWS;
    int s = bbase[b];
    int e = bbase[b + 1];
    int cnt = e - s;

    cur[t] = 0; cur[t + 512] = 0;
    __syncthreads();

    uint2 p[RK];
#pragma unroll
    for (int k = 0; k < RK; ++k) {
        int idx = t + k * 512;     // 0..8191
        if (idx < cnt) {
            p[k] = epack[s + idx];
            atomicAdd(&cur[(p[k].x >> 19) & (BROWS - 1)], 1);
        }
    }
    for (int l = 8192 + t; l < cnt && l < 8192 + OVF; l += 512) {
        uint2 w = epack[s + l];
        ovf[l - 8192] = w;
        atomicAdd(&cur[(w.x >> 19) & (BROWS - 1)], 1);
    }
    __syncthreads();

    // exclusive scan of cur[0..1023], 2 elems/thread
    int c0 = cur[2 * t], c1 = cur[2 * t + 1];
    int ps = c0 + c1;
    stmp[t] = ps;
    __syncthreads();
    for (int off = 1; off < 512; off <<= 1) {
        int u = (t >= off) ? stmp[t - off] : 0;
        __syncthreads();
        stmp[t] += u;
        __syncthreads();
    }
    int pexcl = stmp[t] - ps;      // exclusive over pair sums
    int b0 = s + pexcl;
    int b1 = b0 + c0;
    cur[2 * t] = b0;
    cur[2 * t + 1] = b1;
    if (2 * t < nrows)     row_start[rbase + 2 * t]     = b0;
    if (2 * t + 1 < nrows) row_start[rbase + 2 * t + 1] = b1;
    __syncthreads();

#pragma unroll
    for (int k = 0; k < RK; ++k) {
        int idx = t + k * 512;
        if (idx < cnt) {
            uint2 w = p[k];
            int rl = (w.x >> 19) & (BROWS - 1);
            int pp = atomicAdd(&cur[rl], 1);
            epack[pp] = make_uint2(w.x & 0x7FFFFu, w.y);
        }
    }
    for (int l = 8192 + t; l < cnt && l < 8192 + OVF; l += 512) {
        uint2 w = ovf[l - 8192];
        int rl = (w.x >> 19) & (BROWS - 1);
        int pp = atomicAdd(&cur[rl], 1);
        epack[pp] = make_uint2(w.x & 0x7FFFFu, w.y);
    }
}

// ---------------- init: h0 = ego (bf16) ----------------
__global__ void init_h0(const float4* __restrict__ user4,
                        const float4* __restrict__ item4,
                        ushort4* __restrict__ h4,
                        int total4, int user4n) {
    int i = blockIdx.x * blockDim.x + threadIdx.x;
    if (i >= total4) return;
    float4 v = (i < user4n) ? user4[i] : item4[i - user4n];
    ushort4 b;
    b.x = f32_to_bf16(v.x); b.y = f32_to_bf16(v.y);
    b.z = f32_to_bf16(v.z); b.w = f32_to_bf16(v.w);
    h4[i] = b;
}

// ---------------- gather SpMM core: acc = A_row · x (bf16 gather, f32 acc) ----
__device__ __forceinline__ void spmm_row_acc(const uint2* __restrict__ epack,
                                             const unsigned short* __restrict__ x,
                                             int s, int e, int off, float* __restrict__ out8) {
    float a0[8], a1[8];
#pragma unroll
    for (int k = 0; k < 8; ++k) { a0[k] = 0.f; a1[k] = 0.f; }

    int j = s;
    for (; j + 1 < e; j += 2) {
        u32x2 e0 = __builtin_nontemporal_load((const u32x2*)(epack + j));
        u32x2 e1 = __builtin_nontemporal_load((const u32x2*)(epack + j + 1));
        int c0 = (int)e0.x;
        int c1 = (int)e1.x;
        ushort8_t x0 = *(const ushort8_t*)(x + c0 * DIM + off);
        ushort8_t x1 = *(const ushort8_t*)(x + c1 * DIM + off);
        float v0 = __uint_as_float(e0.y), v1 = __uint_as_float(e1.y);
#pragma unroll
        for (int k = 0; k < 8; ++k) a0[k] += v0 * bf16_to_f32(x0[k]);
#pragma unroll
        for (int k = 0; k < 8; ++k) a1[k] += v1 * bf16_to_f32(x1[k]);
    }
    if (j < e) {
        u32x2 e0 = __builtin_nontemporal_load((const u32x2*)(epack + j));
        int c0 = (int)e0.x;
        ushort8_t x0 = *(const ushort8_t*)(x + c0 * DIM + off);
        float v0 = __uint_as_float(e0.y);
#pragma unroll
        for (int k = 0; k < 8; ++k) a0[k] += v0 * bf16_to_f32(x0[k]);
    }
#pragma unroll
    for (int k = 0; k < 8; ++k) out8[k] = a0[k] + a1[k];
}

// ---------------- gather SpMM: y = A * x (bf16 out), R=4 rows per lane-group ----
__global__ void spmm_gather(const int* __restrict__ row_start,
                            const uint2* __restrict__ epack,
                            const unsigned short* __restrict__ x,
                            unsigned short* __restrict__ y) {
    int tid = threadIdx.x;
    int g = tid >> 3;            // lane-group 0..31
    int lane = tid & 7;          // 8 lanes per row, 8 bf16 each
    int rbase = (blockIdx.x * 32 + g) * 4;   // 4 consecutive rows per group
    if (rbase >= NN) return;     // NN % 4 == 0 -> whole group in or out
    int off = lane << 3;

    int st[5];
#pragma unroll
    for (int q = 0; q < 5; ++q) st[q] = row_start[rbase + q];

#pragma unroll
    for (int q = 0; q < 4; ++q) {
        int row = rbase + q;
        float acc[8];
        spmm_row_acc(epack, x, st[q], st[q + 1], off, acc);
        ushort8_t yb;
#pragma unroll
        for (int k = 0; k < 8; ++k) yb[k] = f32_to_bf16(acc[k]);
        // regular store: y is the next layer's gather source -> keep in L2
        *(ushort8_t*)(y + row * DIM + off) = yb;
    }
}

// ---------------- fused layer 3: out = (h0 + h1 + h2 + A*h2) / 4 (f32 out) ----
// R=4 rows per lane-group; per-row one-shot streams issued before the gather loop.
// ego read as bf16 h0 (exact f32 ego costs +38 MB fetch for <1e-4 accuracy).
__global__ void spmm_final(const int* __restrict__ row_start,
                           const uint2* __restrict__ epack,
                           const unsigned short* __restrict__ x,    // h2 (gather source)
                           const unsigned short* __restrict__ h0,
                           const unsigned short* __restrict__ h1,
                           float* __restrict__ out) {
    int tid = threadIdx.x;
    int g = tid >> 3;
    int lane = tid & 7;
    int rbase = (blockIdx.x * 32 + g) * 4;
    if (rbase >= NN) return;
    int off = lane << 3;

    int st[5];
#pragma unroll
    for (int q = 0; q < 5; ++q) st[q] = row_start[rbase + q];

#pragma unroll
    for (int q = 0; q < 4; ++q) {
        int row = rbase + q;
        // one-shot streams first: latency hides under the gather loop
        ushort8_t b0 = __builtin_nontemporal_load((const ushort8_t*)(h0 + row * DIM + off));
        ushort8_t b1 = __builtin_nontemporal_load((const ushort8_t*)(h1 + row * DIM + off));
        ushort8_t b2 = __builtin_nontemporal_load((const ushort8_t*)(x + row * DIM + off));

        float acc[8];
        spmm_row_acc(epack, x, st[q], st[q + 1], off, acc);

        f32x4 oa, ob;
#pragma unroll
        for (int k = 0; k < 4; ++k)
            oa[k] = (bf16_to_f32(b0[k]) + bf16_to_f32(b1[k]) + bf16_to_f32(b2[k]) + acc[k]) * 0.25f;
#pragma unroll
        for (int k = 0; k < 4; ++k)
            ob[k] = (bf16_to_f32(b0[k + 4]) + bf16_to_f32(b1[k + 4]) + bf16_to_f32(b2[k + 4]) + acc[k + 4]) * 0.25f;

        __builtin_nontemporal_store(oa, (f32x4*)(out + row * DIM + off));
        __builtin_nontemporal_store(ob, (f32x4*)(out + row * DIM + off + 4));
    }
}

extern "C" void kernel_launch(void* const* d_in, const int* in_sizes, int n_in,
                              void* d_out, int out_size, void* d_ws, size_t ws_size,
                              hipStream_t stream) {
    const float* user_emb = (const float*)d_in[0];
    const float* item_emb = (const float*)d_in[1];
    const int*   adj_rows = (const int*)d_in[2];
    const int*   adj_cols = (const int*)d_in[3];
    const float* adj_vals = (const float*)d_in[4];
    float* out = (float*)d_out;

    const int E = in_sizes[2];
    const int total = NN * DIM;            // 19.2M elems
    const int total4 = total / 4;          // 4.8M
    const int user4n = NUM_USERS * DIM / 4;

    // workspace layout (8B-aligned first)
    uint2* epack = (uint2*)d_ws;                           // E uint2 (16 MB)
    unsigned short* hA = (unsigned short*)(epack + E);     // total bf16 (h0)
    unsigned short* hB = hA + total;                       // total bf16 (h1)
    unsigned short* hC = hB + total;                       // total bf16 (h2)
    int* row_start = (int*)(hC + total);                   // NN+1 ints
    int* bcnt  = row_start + NN + 1;                       // 512 ints
    int* bbase = bcnt + 512;                               // 512 ints
    int* bcur  = bbase + 512;                              // 512 ints

    const int TB = 256;
    const int gridV = (total4 + TB - 1) / TB;
    const int gridG = (NN / 4 + 31) / 32;            // 2344 (R=4 rows/group)
    const int nChunksA = (E + CHUNK - 1) / CHUNK;    // 489

    // ---- CSR build ----
    zero_ints<<<1, 512, 0, stream>>>(bcnt, 512);
    bucket_hist<<<nChunksA, 512, 0, stream>>>(adj_rows, bcnt, E);
    scan_buckets<<<1, 512, 0, stream>>>(bcnt, bbase, bcur, row_start, E);
    bin_edges<<<nChunksA, 512, 0, stream>>>(adj_rows, adj_cols, adj_vals, bcur,
                                            epack, E);
    bucket_scatter<<<NB_BUCKETS, 512, 0, stream>>>(bbase, row_start, epack);

    // ---- init h0 ----
    init_h0<<<gridV, TB, 0, stream>>>((const float4*)user_emb, (const float4*)item_emb,
                                      (ushort4*)hA, total4, user4n);

    // ---- SpMM layers 1-2 + fused layer 3 / combine ----
    spmm_gather<<<gridG, TB, 0, stream>>>(row_start, epack, hA, hB); // h1 = A*h0
    spmm_gather<<<gridG, TB, 0, stream>>>(row_start, epack, hB, hC); // h2 = A*h1
    spmm_final<<<gridG, TB, 0, stream>>>(row_start, epack, hC, hA, hB,
                                         out);   // out = (h0+h1+h2+A*h2)/4
}

// Round 7
// 386.729 us; speedup vs baseline: 1.1673x; 1.1673x over previous
//
#include <hip/hip_runtime.h>
#include <hip/hip_bf16.h>

// LightGCN: final = (ego + A·ego + A²·ego + A³·ego) / 4
// CSR build per call (bucket hist/scan + two-phase scatter, all L2-local writes).
// SpMM: bf16 features, 8 lanes/row (16B loads), ONE row per lane-group (R=1:
//   r6 post-mortem — R=4 serial rows cut TLP 4x and cost +54 µs; latency-bound
//   gathers need concurrent chains, not shorter masks).
//   Edge loop UNROLL-4: 4 epack + 4 x-gather loads in flight per group (MLP lever).
//   epack reads NON-TEMPORAL; y stores REGULAR (next layer's gather source, keep in L2).
// Layer 3 fused with final combine (f32 ego: keeps absmax at 4.88e-4).

#define NUM_USERS 100000
#define NUM_ITEMS 200000
#define NN (NUM_USERS + NUM_ITEMS)
#define DIM 64
#define BROWS 1024                              // rows per bucket
#define NB_BUCKETS ((NN + BROWS - 1) / BROWS)   // 293
#define CHUNK 4096                              // edges per binning block
#define RK 16                                   // reg-staged entries/thread (512*16 = 8192)
#define OVF 4096                                // LDS overflow entries in bucket_scatter

typedef unsigned short ushort8_t __attribute__((ext_vector_type(8)));
typedef float f32x4 __attribute__((ext_vector_type(4)));
typedef unsigned int u32x2 __attribute__((ext_vector_type(2)));

__device__ __forceinline__ float bf16_to_f32(unsigned short u) {
    return __uint_as_float(((unsigned int)u) << 16);
}
__device__ __forceinline__ unsigned short f32_to_bf16(float f) {
    unsigned int u = __float_as_uint(f);
    u += 0x7fffu + ((u >> 16) & 1u);   // round-to-nearest-even
    return (unsigned short)(u >> 16);
}

// ---------------- zero an int array ----------------
__global__ void zero_ints(int* __restrict__ p, int n) {
    int i = blockIdx.x * blockDim.x + threadIdx.x;
    if (i < n) p[i] = 0;
}

// ---------------- coarse bucket histogram (293 buckets) ----------------
__global__ __launch_bounds__(512) void bucket_hist(const int* __restrict__ rows,
                                                   int* __restrict__ bcnt, int E) {
    __shared__ int h[512];
    int t = threadIdx.x;
    h[t] = 0;
    __syncthreads();
    int base = blockIdx.x * CHUNK + t * 8;
    if (base + 8 <= E) {
        int4 r0 = *(const int4*)(rows + base);
        int4 r1 = *(const int4*)(rows + base + 4);
        atomicAdd(&h[r0.x >> 10], 1); atomicAdd(&h[r0.y >> 10], 1);
        atomicAdd(&h[r0.z >> 10], 1); atomicAdd(&h[r0.w >> 10], 1);
        atomicAdd(&h[r1.x >> 10], 1); atomicAdd(&h[r1.y >> 10], 1);
        atomicAdd(&h[r1.z >> 10], 1); atomicAdd(&h[r1.w >> 10], 1);
    } else {
        for (int k = 0; k < 8; ++k) {
            int e = base + k;
            if (e < E) atomicAdd(&h[rows[e] >> 10], 1);
        }
    }
    __syncthreads();
    if (t < NB_BUCKETS && h[t] > 0) atomicAdd(&bcnt[t], h[t]);
}

// ---------------- scan bucket counts -> bases; init cursors ----------------
__global__ void scan_buckets(const int* __restrict__ bcnt, int* __restrict__ bbase,
                             int* __restrict__ bcur, int* __restrict__ row_start, int E) {
    __shared__ int lds[512];
    int t = threadIdx.x;
    int v = bcnt[t];               // zeroed beyond NB_BUCKETS
    lds[t] = v;
    __syncthreads();
    for (int off = 1; off < 512; off <<= 1) {
        int u = (t >= off) ? lds[t - off] : 0;
        __syncthreads();
        lds[t] += u;
        __syncthreads();
    }
    int base = lds[t] - v;         // exclusive scan
    if (t <= NB_BUCKETS) bbase[t] = base;   // bbase[NB_BUCKETS] == E
    if (t < NB_BUCKETS)  bcur[t] = base;
    if (t == 0) row_start[NN] = E;
}

// ---------------- phase A: LDS-staged bucket binning ----------------
__global__ __launch_bounds__(512) void bin_edges(const int* __restrict__ rows,
                                                 const int* __restrict__ cols,
                                                 const float* __restrict__ vals,
                                                 int* __restrict__ bcur,
                                                 uint2* __restrict__ epack, int E) {
    __shared__ int lcnt[512];
    __shared__ int lscan[512];
    __shared__ int lcur[512];
    __shared__ int gbase[512];
    __shared__ uint2 stage[CHUNK];
    __shared__ int dstg[CHUNK];

    int t = threadIdx.x;
    int base = blockIdx.x * CHUNK;
    int n = E - base; if (n > CHUNK) n = CHUNK;

    lcnt[t] = 0;
    __syncthreads();

    int r[8], c[8], b[8];
    unsigned int vb[8];
    int ebase = base + t * 8;
    if (ebase + 8 <= E) {
        int4 r0 = *(const int4*)(rows + ebase);
        int4 r1 = *(const int4*)(rows + ebase + 4);
        int4 c0 = *(const int4*)(cols + ebase);
        int4 c1 = *(const int4*)(cols + ebase + 4);
        float4 v0 = *(const float4*)(vals + ebase);
        float4 v1 = *(const float4*)(vals + ebase + 4);
        r[0]=r0.x; r[1]=r0.y; r[2]=r0.z; r[3]=r0.w; r[4]=r1.x; r[5]=r1.y; r[6]=r1.z; r[7]=r1.w;
        c[0]=c0.x; c[1]=c0.y; c[2]=c0.z; c[3]=c0.w; c[4]=c1.x; c[5]=c1.y; c[6]=c1.z; c[7]=c1.w;
        vb[0]=__float_as_uint(v0.x); vb[1]=__float_as_uint(v0.y);
        vb[2]=__float_as_uint(v0.z); vb[3]=__float_as_uint(v0.w);
        vb[4]=__float_as_uint(v1.x); vb[5]=__float_as_uint(v1.y);
        vb[6]=__float_as_uint(v1.z); vb[7]=__float_as_uint(v1.w);
#pragma unroll
        for (int k = 0; k < 8; ++k) b[k] = r[k] >> 10;
    } else {
#pragma unroll
        for (int k = 0; k < 8; ++k) {
            int e = ebase + k;
            if (e < E) { r[k] = rows[e]; c[k] = cols[e]; vb[k] = __float_as_uint(vals[e]); b[k] = r[k] >> 10; }
            else b[k] = -1;
        }
    }
#pragma unroll
    for (int k = 0; k < 8; ++k)
        if (b[k] >= 0) atomicAdd(&lcnt[b[k]], 1);
    __syncthreads();

    // Hillis-Steele inclusive scan over 512 entries
    int val = lcnt[t];
    lscan[t] = val;
    __syncthreads();
    for (int off = 1; off < 512; off <<= 1) {
        int u = (t >= off) ? lscan[t - off] : 0;
        __syncthreads();
        lscan[t] += u;
        __syncthreads();
    }
    int excl = lscan[t] - val;
    lscan[t] = excl;          // exclusive local base (own-slot rewrite)
    lcur[t]  = excl;
    if (t < NB_BUCKETS && val > 0)
        gbase[t] = atomicAdd(&bcur[t], val);
    __syncthreads();

    // reorder into LDS (sorted by bucket), record global dst per slot
#pragma unroll
    for (int k = 0; k < 8; ++k) {
        int bb = b[k];
        if (bb >= 0) {
            int l = atomicAdd(&lcur[bb], 1);
            unsigned int w0 = (unsigned int)c[k] | (((unsigned int)(r[k] & (BROWS - 1))) << 19);
            stage[l] = make_uint2(w0, vb[k]);
            dstg[l] = gbase[bb] + (l - lscan[bb]);
        }
    }
    __syncthreads();

    // coalesced run writes
    for (int l = t; l < n; l += 512)
        epack[dstg[l]] = stage[l];
}

// ---------------- phase B: per-bucket row-hist + scan + exact CSR placement ----
__global__ __launch_bounds__(512) void bucket_scatter(const int* __restrict__ bbase,
                                                      int* __restrict__ row_start,
                                                      uint2* __restrict__ epack) {
    __shared__ int cur[BROWS];     // hist -> cursor
    __shared__ int stmp[512];
    __shared__ uint2 ovf[OVF];
    int b = blockIdx.x;
    int t = threadIdx.x;
    int rbase = b << 10;
    int nrows = NN - rbase; if (nrows > BROWS) nrows = BROWS;
    int s = bbase[b];
    int e = bbase[b + 1];
    int cnt = e - s;

    cur[t] = 0; cur[t + 512] = 0;
    __syncthreads();

    uint2 p[RK];
#pragma unroll
    for (int k = 0; k < RK; ++k) {
        int idx = t + k * 512;     // 0..8191
        if (idx < cnt) {
            p[k] = epack[s + idx];
            atomicAdd(&cur[(p[k].x >> 19) & (BROWS - 1)], 1);
        }
    }
    for (int l = 8192 + t; l < cnt && l < 8192 + OVF; l += 512) {
        uint2 w = epack[s + l];
        ovf[l - 8192] = w;
        atomicAdd(&cur[(w.x >> 19) & (BROWS - 1)], 1);
    }
    __syncthreads();

    // exclusive scan of cur[0..1023], 2 elems/thread
    int c0 = cur[2 * t], c1 = cur[2 * t + 1];
    int ps = c0 + c1;
    stmp[t] = ps;
    __syncthreads();
    for (int off = 1; off < 512; off <<= 1) {
        int u = (t >= off) ? stmp[t - off] : 0;
        __syncthreads();
        stmp[t] += u;
        __syncthreads();
    }
    int pexcl = stmp[t] - ps;      // exclusive over pair sums
    int b0 = s + pexcl;
    int b1 = b0 + c0;
    cur[2 * t] = b0;
    cur[2 * t + 1] = b1;
    if (2 * t < nrows)     row_start[rbase + 2 * t]     = b0;
    if (2 * t + 1 < nrows) row_start[rbase + 2 * t + 1] = b1;
    __syncthreads();

#pragma unroll
    for (int k = 0; k < RK; ++k) {
        int idx = t + k * 512;
        if (idx < cnt) {
            uint2 w = p[k];
            int rl = (w.x >> 19) & (BROWS - 1);
            int pp = atomicAdd(&cur[rl], 1);
            epack[pp] = make_uint2(w.x & 0x7FFFFu, w.y);
        }
    }
    for (int l = 8192 + t; l < cnt && l < 8192 + OVF; l += 512) {
        uint2 w = ovf[l - 8192];
        int rl = (w.x >> 19) & (BROWS - 1);
        int pp = atomicAdd(&cur[rl], 1);
        epack[pp] = make_uint2(w.x & 0x7FFFFu, w.y);
    }
}

// ---------------- init: h0 = ego (bf16) ----------------
__global__ void init_h0(const float4* __restrict__ user4,
                        const float4* __restrict__ item4,
                        ushort4* __restrict__ h4,
                        int total4, int user4n) {
    int i = blockIdx.x * blockDim.x + threadIdx.x;
    if (i >= total4) return;
    float4 v = (i < user4n) ? user4[i] : item4[i - user4n];
    ushort4 b;
    b.x = f32_to_bf16(v.x); b.y = f32_to_bf16(v.y);
    b.z = f32_to_bf16(v.z); b.w = f32_to_bf16(v.w);
    h4[i] = b;
}

// ---------------- gather SpMM core: acc = A_row · x (bf16 gather, f32 acc) ----
// UNROLL-4 main loop: 4 epack + 4 x-gather loads in flight (loads independent of acc).
// Dual accumulators only (VGPR budget); tail = 2-step then 1-step.
__device__ __forceinline__ void spmm_row_acc(const uint2* __restrict__ epack,
                                             const unsigned short* __restrict__ x,
                                             int s, int e, int off, float* __restrict__ out8) {
    float a0[8], a1[8];
#pragma unroll
    for (int k = 0; k < 8; ++k) { a0[k] = 0.f; a1[k] = 0.f; }

    int j = s;
    for (; j + 3 < e; j += 4) {
        u32x2 e0 = __builtin_nontemporal_load((const u32x2*)(epack + j));
        u32x2 e1 = __builtin_nontemporal_load((const u32x2*)(epack + j + 1));
        u32x2 e2 = __builtin_nontemporal_load((const u32x2*)(epack + j + 2));
        u32x2 e3 = __builtin_nontemporal_load((const u32x2*)(epack + j + 3));
        ushort8_t x0 = *(const ushort8_t*)(x + (int)e0.x * DIM + off);
        ushort8_t x1 = *(const ushort8_t*)(x + (int)e1.x * DIM + off);
        ushort8_t x2 = *(const ushort8_t*)(x + (int)e2.x * DIM + off);
        ushort8_t x3 = *(const ushort8_t*)(x + (int)e3.x * DIM + off);
        float v0 = __uint_as_float(e0.y), v1 = __uint_as_float(e1.y);
        float v2 = __uint_as_float(e2.y), v3 = __uint_as_float(e3.y);
#pragma unroll
        for (int k = 0; k < 8; ++k) a0[k] += v0 * bf16_to_f32(x0[k]);
#pragma unroll
        for (int k = 0; k < 8; ++k) a1[k] += v1 * bf16_to_f32(x1[k]);
#pragma unroll
        for (int k = 0; k < 8; ++k) a0[k] += v2 * bf16_to_f32(x2[k]);
#pragma unroll
        for (int k = 0; k < 8; ++k) a1[k] += v3 * bf16_to_f32(x3[k]);
    }
    if (j + 1 < e) {
        u32x2 e0 = __builtin_nontemporal_load((const u32x2*)(epack + j));
        u32x2 e1 = __builtin_nontemporal_load((const u32x2*)(epack + j + 1));
        ushort8_t x0 = *(const ushort8_t*)(x + (int)e0.x * DIM + off);
        ushort8_t x1 = *(const ushort8_t*)(x + (int)e1.x * DIM + off);
        float v0 = __uint_as_float(e0.y), v1 = __uint_as_float(e1.y);
#pragma unroll
        for (int k = 0; k < 8; ++k) a0[k] += v0 * bf16_to_f32(x0[k]);
#pragma unroll
        for (int k = 0; k < 8; ++k) a1[k] += v1 * bf16_to_f32(x1[k]);
        j += 2;
    }
    if (j < e) {
        u32x2 e0 = __builtin_nontemporal_load((const u32x2*)(epack + j));
        ushort8_t x0 = *(const ushort8_t*)(x + (int)e0.x * DIM + off);
        float v0 = __uint_as_float(e0.y);
#pragma unroll
        for (int k = 0; k < 8; ++k) a0[k] += v0 * bf16_to_f32(x0[k]);
    }
#pragma unroll
    for (int k = 0; k < 8; ++k) out8[k] = a0[k] + a1[k];
}

// ---------------- gather SpMM: y = A * x (bf16 out), 1 row per lane-group ----
__global__ void spmm_gather(const int* __restrict__ row_start,
                            const uint2* __restrict__ epack,
                            const unsigned short* __restrict__ x,
                            unsigned short* __restrict__ y) {
    int tid = threadIdx.x;
    int sub = tid >> 3;          // 0..31 rows per block
    int lane = tid & 7;          // 8 lanes per row, 8 bf16 each
    int row = blockIdx.x * 32 + sub;
    if (row >= NN) return;
    int s = row_start[row];
    int e = row_start[row + 1];
    int off = lane << 3;

    float acc[8];
    spmm_row_acc(epack, x, s, e, off, acc);

    ushort8_t yb;
#pragma unroll
    for (int k = 0; k < 8; ++k) yb[k] = f32_to_bf16(acc[k]);
    // regular store: y is the next layer's gather source -> keep in L2
    *(ushort8_t*)(y + row * DIM + off) = yb;
}

// ---------------- fused layer 3: out = (ego + h1 + h2 + A*h2) / 4 (f32 out) ----
// Streaming loads issued BEFORE the gather loop so their latency hides under it.
__global__ void spmm_final(const int* __restrict__ row_start,
                           const uint2* __restrict__ epack,
                           const unsigned short* __restrict__ x,    // h2 (gather source)
                           const unsigned short* __restrict__ h1,
                           const float* __restrict__ user_emb,
                           const float* __restrict__ item_emb,
                           float* __restrict__ out) {
    int tid = threadIdx.x;
    int sub = tid >> 3;
    int lane = tid & 7;
    int row = blockIdx.x * 32 + sub;
    if (row >= NN) return;
    int s = row_start[row];
    int e = row_start[row + 1];
    int off = lane << 3;

    // issue one-shot streams first (independent of gather loop)
    const float* ego = (row < NUM_USERS) ? (user_emb + row * DIM)
                                         : (item_emb + (row - NUM_USERS) * DIM);
    f32x4 ea = __builtin_nontemporal_load((const f32x4*)(ego + off));
    f32x4 eb = __builtin_nontemporal_load((const f32x4*)(ego + off + 4));
    ushort8_t b1 = __builtin_nontemporal_load((const ushort8_t*)(h1 + row * DIM + off));
    ushort8_t b2 = __builtin_nontemporal_load((const ushort8_t*)(x + row * DIM + off));

    float acc[8];
    spmm_row_acc(epack, x, s, e, off, acc);

    f32x4 oa, ob;
#pragma unroll
    for (int k = 0; k < 4; ++k)
        oa[k] = (ea[k] + bf16_to_f32(b1[k]) + bf16_to_f32(b2[k]) + acc[k]) * 0.25f;
#pragma unroll
    for (int k = 0; k < 4; ++k)
        ob[k] = (eb[k] + bf16_to_f32(b1[k + 4]) + bf16_to_f32(b2[k + 4]) + acc[k + 4]) * 0.25f;

    __builtin_nontemporal_store(oa, (f32x4*)(out + row * DIM + off));
    __builtin_nontemporal_store(ob, (f32x4*)(out + row * DIM + off + 4));
}

extern "C" void kernel_launch(void* const* d_in, const int* in_sizes, int n_in,
                              void* d_out, int out_size, void* d_ws, size_t ws_size,
                              hipStream_t stream) {
    const float* user_emb = (const float*)d_in[0];
    const float* item_emb = (const float*)d_in[1];
    const int*   adj_rows = (const int*)d_in[2];
    const int*   adj_cols = (const int*)d_in[3];
    const float* adj_vals = (const float*)d_in[4];
    float* out = (float*)d_out;

    const int E = in_sizes[2];
    const int total = NN * DIM;            // 19.2M elems
    const int total4 = total / 4;          // 4.8M
    const int user4n = NUM_USERS * DIM / 4;

    // workspace layout (8B-aligned first)
    uint2* epack = (uint2*)d_ws;                           // E uint2 (16 MB)
    unsigned short* hA = (unsigned short*)(epack + E);     // total bf16 (h0)
    unsigned short* hB = hA + total;                       // total bf16 (h1)
    unsigned short* hC = hB + total;                       // total bf16 (h2)
    int* row_start = (int*)(hC + total);                   // NN+1 ints
    int* bcnt  = row_start + NN + 1;                       // 512 ints
    int* bbase = bcnt + 512;                               // 512 ints
    int* bcur  = bbase + 512;                              // 512 ints

    const int TB = 256;
    const int gridV = (total4 + TB - 1) / TB;
    const int gridG = (NN + 31) / 32;                // 9375 (1 row per lane-group)
    const int nChunksA = (E + CHUNK - 1) / CHUNK;    // 489

    // ---- CSR build ----
    zero_ints<<<1, 512, 0, stream>>>(bcnt, 512);
    bucket_hist<<<nChunksA, 512, 0, stream>>>(adj_rows, bcnt, E);
    scan_buckets<<<1, 512, 0, stream>>>(bcnt, bbase, bcur, row_start, E);
    bin_edges<<<nChunksA, 512, 0, stream>>>(adj_rows, adj_cols, adj_vals, bcur,
                                            epack, E);
    bucket_scatter<<<NB_BUCKETS, 512, 0, stream>>>(bbase, row_start, epack);

    // ---- init h0 ----
    init_h0<<<gridV, TB, 0, stream>>>((const float4*)user_emb, (const float4*)item_emb,
                                      (ushort4*)hA, total4, user4n);

    // ---- SpMM layers 1-2 + fused layer 3 / combine ----
    spmm_gather<<<gridG, TB, 0, stream>>>(row_start, epack, hA, hB); // h1 = A*h0
    spmm_gather<<<gridG, TB, 0, stream>>>(row_start, epack, hB, hC); // h2 = A*h1
    spmm_final<<<gridG, TB, 0, stream>>>(row_start, epack, hC, hB,
                                         user_emb, item_emb, out);   // out = (ego+h1+h2+A*h2)/4
}